// Round 4
// baseline (413.167 us; speedup 1.0000x reference)
//
#include <hip/hip_runtime.h>

#define N_NODES 50000
#define N_EDGES 800000
#define D 64
#define CAP 64

typedef float vf4 __attribute__((ext_vector_type(4)));

// ---------------- K1: score + exp + bucket insert ----------------
// 4 lanes per edge, 64B/lane of e and of h_src (4 x float4 each -> 8
// independent loads in flight). Nontemporal loads for streamed-once e.
// Leader lane does exp and pushes {src, exp_bits} into dst's slot list.
__global__ __launch_bounds__(256) void k1_score(
    const vf4* __restrict__ h_src4, const vf4* __restrict__ e4,
    const int* __restrict__ src, const int* __restrict__ dst,
    int* __restrict__ count, int2* __restrict__ slots) {
    int t = threadIdx.x;
    int edge = blockIdx.x * 64 + (t >> 2);   // grid sized exactly
    int l4 = t & 3;
    int s = src[edge];
    const vf4* hp = h_src4 + (size_t)s * 16 + l4;
    const vf4* ep = e4 + (size_t)edge * 16 + l4;
    vf4 e0 = __builtin_nontemporal_load(ep + 0);
    vf4 e1 = __builtin_nontemporal_load(ep + 4);
    vf4 e2 = __builtin_nontemporal_load(ep + 8);
    vf4 e3 = __builtin_nontemporal_load(ep + 12);
    vf4 u0 = hp[0];
    vf4 u1 = hp[4];
    vf4 u2 = hp[8];
    vf4 u3 = hp[12];
    float v = u0[0]*e0[0] + u0[1]*e0[1] + u0[2]*e0[2] + u0[3]*e0[3]
            + u1[0]*e1[0] + u1[1]*e1[1] + u1[2]*e1[2] + u1[3]*e1[3]
            + u2[0]*e2[0] + u2[1]*e2[1] + u2[2]*e2[2] + u2[3]*e2[3]
            + u3[0]*e3[0] + u3[1]*e3[1] + u3[2]*e3[2] + u3[3]*e3[3];
    v += __shfl_xor(v, 1);
    v += __shfl_xor(v, 2);
    if (l4 == 0) {
        float ex = expf(v);
        int d = dst[edge];
        int pos = atomicAdd(&count[d], 1);
        if (pos < CAP)
            slots[(size_t)d * CAP + pos] = make_int2(s, __float_as_int(ex));
    }
}

// ---------------- K2+K3 fused: gather-aggregate + linear ----------------
// 16 lanes per node, 16 nodes per block. Batch-16 cooperative slot load +
// shfl broadcast; 8 independent h_src gathers in flight. Epilogue reads ht
// as float4 (b128) to cut LDS op count.
__global__ __launch_bounds__(256) void k2k3(
    const vf4* __restrict__ h_src4, const vf4* __restrict__ h_dst4,
    const int* __restrict__ count, const int2* __restrict__ slots,
    const float* __restrict__ W, const float* __restrict__ b,
    float* __restrict__ out) {
    __shared__ float Wl[128 * 64];                 // transposed: Wl[k*64+o]
    __shared__ __align__(16) float ht[16][128];
    int t = threadIdx.x;
    for (int i = t; i < 128 * 64; i += 256) {
        int o = i >> 7, k = i & 127;               // W is [64][128] row-major
        Wl[k * 64 + o] = W[i];
    }
    int node0 = blockIdx.x * 16;                   // 50000/16 = 3125 exact
    int n = t >> 4;
    int l16 = t & 15;
    int node = node0 + n;
    int cnt = count[node];
    cnt = cnt < CAP ? cnt : CAP;
    const int2* row = slots + (size_t)node * CAP;
    vf4 acc = {0.f, 0.f, 0.f, 0.f};
    float dsum = 0.f;
    for (int base = 0; base < cnt; base += 16) {
        int m = cnt - base;
        m = m > 16 ? 16 : m;
        int2 se = make_int2(0, 0);
        if (l16 < m) se = row[base + l16];
        int j = 0;
        for (; j + 8 <= m; j += 8) {
            int   s0 = __shfl(se.x, j + 0, 16); float w0 = __int_as_float(__shfl(se.y, j + 0, 16));
            int   s1 = __shfl(se.x, j + 1, 16); float w1 = __int_as_float(__shfl(se.y, j + 1, 16));
            int   s2 = __shfl(se.x, j + 2, 16); float w2 = __int_as_float(__shfl(se.y, j + 2, 16));
            int   s3 = __shfl(se.x, j + 3, 16); float w3 = __int_as_float(__shfl(se.y, j + 3, 16));
            int   s4 = __shfl(se.x, j + 4, 16); float w4 = __int_as_float(__shfl(se.y, j + 4, 16));
            int   s5 = __shfl(se.x, j + 5, 16); float w5 = __int_as_float(__shfl(se.y, j + 5, 16));
            int   s6 = __shfl(se.x, j + 6, 16); float w6 = __int_as_float(__shfl(se.y, j + 6, 16));
            int   s7 = __shfl(se.x, j + 7, 16); float w7 = __int_as_float(__shfl(se.y, j + 7, 16));
            vf4 g0 = h_src4[(size_t)s0 * 16 + l16];
            vf4 g1 = h_src4[(size_t)s1 * 16 + l16];
            vf4 g2 = h_src4[(size_t)s2 * 16 + l16];
            vf4 g3 = h_src4[(size_t)s3 * 16 + l16];
            vf4 g4 = h_src4[(size_t)s4 * 16 + l16];
            vf4 g5 = h_src4[(size_t)s5 * 16 + l16];
            vf4 g6 = h_src4[(size_t)s6 * 16 + l16];
            vf4 g7 = h_src4[(size_t)s7 * 16 + l16];
            acc += w0 * g0; dsum += w0;
            acc += w1 * g1; dsum += w1;
            acc += w2 * g2; dsum += w2;
            acc += w3 * g3; dsum += w3;
            acc += w4 * g4; dsum += w4;
            acc += w5 * g5; dsum += w5;
            acc += w6 * g6; dsum += w6;
            acc += w7 * g7; dsum += w7;
        }
        for (; j < m; ++j) {
            int s0 = __shfl(se.x, j, 16);
            float w0 = __int_as_float(__shfl(se.y, j, 16));
            vf4 g0 = h_src4[(size_t)s0 * 16 + l16];
            acc += w0 * g0; dsum += w0;
        }
    }
    float inv = (cnt > 0) ? 1.f / dsum : 0.f;
    acc *= inv;
    vf4 hd = h_dst4[(size_t)node * 16 + l16];
    ((vf4*)&ht[n][0])[l16] = hd;
    ((vf4*)&ht[n][64])[l16] = acc;
    __syncthreads();

    int o = t & 63;
    int g = t >> 6;                                // nodes g*4 .. g*4+3
    float bias = b[o];
    float a0 = bias, a1 = bias, a2 = bias, a3 = bias;
    const float* h0 = &ht[g * 4 + 0][0];
    const float* h1 = &ht[g * 4 + 1][0];
    const float* h2 = &ht[g * 4 + 2][0];
    const float* h3 = &ht[g * 4 + 3][0];
    #pragma unroll
    for (int k = 0; k < 128; k += 4) {
        float w0 = Wl[(k + 0) * 64 + o];
        float w1 = Wl[(k + 1) * 64 + o];
        float w2 = Wl[(k + 2) * 64 + o];
        float w3 = Wl[(k + 3) * 64 + o];
        vf4 p0 = *(const vf4*)&h0[k];
        vf4 p1 = *(const vf4*)&h1[k];
        vf4 p2 = *(const vf4*)&h2[k];
        vf4 p3 = *(const vf4*)&h3[k];
        a0 += p0[0]*w0 + p0[1]*w1 + p0[2]*w2 + p0[3]*w3;
        a1 += p1[0]*w0 + p1[1]*w1 + p1[2]*w2 + p1[3]*w3;
        a2 += p2[0]*w0 + p2[1]*w1 + p2[2]*w2 + p2[3]*w3;
        a3 += p3[0]*w0 + p3[1]*w1 + p3[2]*w2 + p3[3]*w3;
    }
    out[(size_t)(node0 + g * 4 + 0) * 64 + o] = a0;
    out[(size_t)(node0 + g * 4 + 1) * 64 + o] = a1;
    out[(size_t)(node0 + g * 4 + 2) * 64 + o] = a2;
    out[(size_t)(node0 + g * 4 + 3) * 64 + o] = a3;
}

extern "C" void kernel_launch(void* const* d_in, const int* in_sizes, int n_in,
                              void* d_out, int out_size, void* d_ws, size_t ws_size,
                              hipStream_t stream) {
    const float* h_src = (const float*)d_in[0];
    const float* h_dst = (const float*)d_in[1];
    const float* e     = (const float*)d_in[2];
    const int*   src   = (const int*)d_in[3];
    const int*   dst   = (const int*)d_in[4];
    const float* W     = (const float*)d_in[5];
    const float* b     = (const float*)d_in[6];
    float* out = (float*)d_out;

    // workspace: count[N] | slots[N*CAP int2]
    auto align256 = [](size_t x) { return (x + 255) & ~(size_t)255; };
    char* ws = (char*)d_ws;
    int*  count = (int*)ws;
    int2* slots = (int2*)(ws + align256((size_t)N_NODES * 4));

    hipMemsetAsync(count, 0, (size_t)N_NODES * 4, stream);

    k1_score<<<N_EDGES / 64, 256, 0, stream>>>(
        (const vf4*)h_src, (const vf4*)e, src, dst, count, slots);
    k2k3<<<N_NODES / 16, 256, 0, stream>>>(
        (const vf4*)h_src, (const vf4*)h_dst, count, slots, W, b, out);
}

// Round 5
// 403.329 us; speedup vs baseline: 1.0244x; 1.0244x over previous
//
#include <hip/hip_runtime.h>

#define N_NODES 50000
#define N_EDGES 800000
#define D 64
#define CAP 64

typedef float vf4 __attribute__((ext_vector_type(4)));

// ---------------- K1: score + exp + bucket insert ----------------
// 8 lanes per edge, 32B/lane (2 x float4). Nontemporal loads for the
// streamed-once e array so it doesn't evict the hot h_src set from L2.
// Leader lane does exp and pushes {src, exp_bits} into dst's slot list.
__global__ __launch_bounds__(256) void k1_score(
    const vf4* __restrict__ h_src4, const vf4* __restrict__ e4,
    const int* __restrict__ src, const int* __restrict__ dst,
    int* __restrict__ count, int2* __restrict__ slots) {
    int t = threadIdx.x;
    int edge = blockIdx.x * 32 + (t >> 3);   // grid sized exactly
    int l8 = t & 7;
    int s = src[edge];
    const vf4* hp = h_src4 + (size_t)s * 16;
    const vf4* ep = e4 + (size_t)edge * 16;
    vf4 u0 = hp[l8];
    vf4 u1 = hp[8 + l8];
    vf4 e0 = __builtin_nontemporal_load(ep + l8);
    vf4 e1 = __builtin_nontemporal_load(ep + 8 + l8);
    float v = u0[0]*e0[0] + u0[1]*e0[1] + u0[2]*e0[2] + u0[3]*e0[3]
            + u1[0]*e1[0] + u1[1]*e1[1] + u1[2]*e1[2] + u1[3]*e1[3];
    v += __shfl_xor(v, 1);
    v += __shfl_xor(v, 2);
    v += __shfl_xor(v, 4);
    if (l8 == 0) {
        float ex = expf(v);
        int d = dst[edge];
        int pos = atomicAdd(&count[d], 1);
        if (pos < CAP)
            slots[(size_t)d * CAP + pos] = make_int2(s, __float_as_int(ex));
    }
}

// ---------------- K2+K3 fused: gather-aggregate + linear ----------------
// 16 lanes per node, 16 nodes per block. Batch-16 cooperative slot load with
// zero-padding (w=0 lanes contribute nothing) -> branch-free fully-unrolled
// 16 gathers in flight, no remainder loop. h_sum stays on-chip; epilogue
// computes out = [h_dst | h_sum] @ W^T + b with vectorized ht reads.
__global__ __launch_bounds__(256) void k2k3(
    const vf4* __restrict__ h_src4, const vf4* __restrict__ h_dst4,
    const int* __restrict__ count, const int2* __restrict__ slots,
    const float* __restrict__ W, const float* __restrict__ b,
    float* __restrict__ out) {
    __shared__ float Wl[128 * 64];                 // transposed: Wl[k*64+o]
    __shared__ __align__(16) float ht[16][128];
    int t = threadIdx.x;
    for (int i = t; i < 128 * 64; i += 256) {
        int o = i >> 7, k = i & 127;               // W is [64][128] row-major
        Wl[k * 64 + o] = W[i];
    }
    int node0 = blockIdx.x * 16;                   // 50000/16 = 3125 exact
    int n = t >> 4;
    int l16 = t & 15;
    int node = node0 + n;
    int cnt = count[node];
    cnt = cnt < CAP ? cnt : CAP;
    const int2* row = slots + (size_t)node * CAP;
    vf4 acc = {0.f, 0.f, 0.f, 0.f};
    float dsum = 0.f;
    for (int base = 0; base < cnt; base += 16) {
        int rem = cnt - base;
        // zero-padded cooperative slot load: lanes >= rem contribute w=0,
        // s=0 (harmless gather of h_src[0] scaled by 0.0)
        int2 se = make_int2(0, 0);
        if (l16 < rem) se = row[base + l16];
        #pragma unroll
        for (int j = 0; j < 16; ++j) {
            int   sj = __shfl(se.x, j, 16);
            float wj = __int_as_float(__shfl(se.y, j, 16));
            vf4   gj = h_src4[(size_t)sj * 16 + l16];
            acc += wj * gj;
            dsum += wj;
        }
    }
    float inv = (cnt > 0) ? 1.f / dsum : 0.f;
    acc *= inv;
    vf4 hd = h_dst4[(size_t)node * 16 + l16];
    ((vf4*)&ht[n][0])[l16] = hd;
    ((vf4*)&ht[n][64])[l16] = acc;
    __syncthreads();

    int o = t & 63;
    int g = t >> 6;                                // nodes g*4 .. g*4+3
    float bias = b[o];
    float a0 = bias, a1 = bias, a2 = bias, a3 = bias;
    const float* h0 = &ht[g * 4 + 0][0];
    const float* h1 = &ht[g * 4 + 1][0];
    const float* h2 = &ht[g * 4 + 2][0];
    const float* h3 = &ht[g * 4 + 3][0];
    #pragma unroll
    for (int k = 0; k < 128; k += 4) {
        float w0 = Wl[(k + 0) * 64 + o];
        float w1 = Wl[(k + 1) * 64 + o];
        float w2 = Wl[(k + 2) * 64 + o];
        float w3 = Wl[(k + 3) * 64 + o];
        vf4 p0 = *(const vf4*)&h0[k];
        vf4 p1 = *(const vf4*)&h1[k];
        vf4 p2 = *(const vf4*)&h2[k];
        vf4 p3 = *(const vf4*)&h3[k];
        a0 += p0[0]*w0 + p0[1]*w1 + p0[2]*w2 + p0[3]*w3;
        a1 += p1[0]*w0 + p1[1]*w1 + p1[2]*w2 + p1[3]*w3;
        a2 += p2[0]*w0 + p2[1]*w1 + p2[2]*w2 + p2[3]*w3;
        a3 += p3[0]*w0 + p3[1]*w1 + p3[2]*w2 + p3[3]*w3;
    }
    out[(size_t)(node0 + g * 4 + 0) * 64 + o] = a0;
    out[(size_t)(node0 + g * 4 + 1) * 64 + o] = a1;
    out[(size_t)(node0 + g * 4 + 2) * 64 + o] = a2;
    out[(size_t)(node0 + g * 4 + 3) * 64 + o] = a3;
}

extern "C" void kernel_launch(void* const* d_in, const int* in_sizes, int n_in,
                              void* d_out, int out_size, void* d_ws, size_t ws_size,
                              hipStream_t stream) {
    const float* h_src = (const float*)d_in[0];
    const float* h_dst = (const float*)d_in[1];
    const float* e     = (const float*)d_in[2];
    const int*   src   = (const int*)d_in[3];
    const int*   dst   = (const int*)d_in[4];
    const float* W     = (const float*)d_in[5];
    const float* b     = (const float*)d_in[6];
    float* out = (float*)d_out;

    // workspace: count[N] | slots[N*CAP int2]
    auto align256 = [](size_t x) { return (x + 255) & ~(size_t)255; };
    char* ws = (char*)d_ws;
    int*  count = (int*)ws;
    int2* slots = (int2*)(ws + align256((size_t)N_NODES * 4));

    hipMemsetAsync(count, 0, (size_t)N_NODES * 4, stream);

    k1_score<<<N_EDGES / 32, 256, 0, stream>>>(
        (const vf4*)h_src, (const vf4*)e, src, dst, count, slots);
    k2k3<<<N_NODES / 16, 256, 0, stream>>>(
        (const vf4*)h_src, (const vf4*)h_dst, count, slots, W, b, out);
}

// Round 6
// 399.549 us; speedup vs baseline: 1.0341x; 1.0095x over previous
//
#include <hip/hip_runtime.h>

#define N_NODES 50000
#define N_EDGES 800000
#define D 64
#define CAP 64

typedef float vf4 __attribute__((ext_vector_type(4)));

// ---------------- K1: bucket build only ----------------
// 1 thread per edge: push {src, edge} onto dst's slot list. No feature data
// touched -> ~13 MB of traffic total.
__global__ __launch_bounds__(256) void k1_bucket(
    const int* __restrict__ src, const int* __restrict__ dst,
    int* __restrict__ count, int2* __restrict__ slots) {
    int i = blockIdx.x * 256 + threadIdx.x;   // grid sized exactly
    int s = src[i];
    int d = dst[i];
    int pos = atomicAdd(&count[d], 1);
    if (pos < CAP)
        slots[(size_t)d * CAP + pos] = make_int2(s, i);
}

// ---------------- K2+K3 fused: dot+exp+aggregate + linear ----------------
// 16 lanes per node, 16 nodes per block. Per batch of 8 edges: cooperative
// slot load; per edge j: gather h_src[s_j] and e[edge_j] rows (256 B each),
// partial dot + 4-step shfl reduce, all-lane expf, then acc += w*u with u
// still in registers (no reload, no second pass). e is read exactly once
// chip-wide here. Epilogue: out = [h_dst | h_sum] @ W^T + b.
__global__ __launch_bounds__(256) void k2k3(
    const vf4* __restrict__ h_src4, const vf4* __restrict__ h_dst4,
    const vf4* __restrict__ e4,
    const int* __restrict__ count, const int2* __restrict__ slots,
    const float* __restrict__ W, const float* __restrict__ b,
    float* __restrict__ out) {
    __shared__ float Wl[128 * 64];                 // transposed: Wl[k*64+o]
    __shared__ __align__(16) float ht[16][128];
    int t = threadIdx.x;
    for (int i = t; i < 128 * 64; i += 256) {
        int o = i >> 7, k = i & 127;               // W is [64][128] row-major
        Wl[k * 64 + o] = W[i];
    }
    int node0 = blockIdx.x * 16;                   // 50000/16 = 3125 exact
    int n = t >> 4;
    int l16 = t & 15;
    int node = node0 + n;
    int cnt = count[node];
    cnt = cnt < CAP ? cnt : CAP;
    const int2* row = slots + (size_t)node * CAP;
    vf4 acc = {0.f, 0.f, 0.f, 0.f};
    float dsum = 0.f;
    for (int base = 0; base < cnt; base += 8) {
        // cooperative slot load: lanes 0..7 hold this batch's {src, edge};
        // padded lanes get {0,0} (safe addresses, weight zeroed below)
        int2 se = make_int2(0, 0);
        if (l16 < 8 && base + l16 < cnt) se = row[base + l16];
        #pragma unroll
        for (int j = 0; j < 8; ++j) {
            int sj = __shfl(se.x, j, 16);
            int ej = __shfl(se.y, j, 16);
            vf4 u  = h_src4[(size_t)sj * 16 + l16];
            vf4 ev = e4[(size_t)ej * 16 + l16];
            float p = u[0]*ev[0] + u[1]*ev[1] + u[2]*ev[2] + u[3]*ev[3];
            p += __shfl_xor(p, 1, 16);
            p += __shfl_xor(p, 2, 16);
            p += __shfl_xor(p, 4, 16);
            p += __shfl_xor(p, 8, 16);
            float w = expf(p);
            w = (base + j < cnt) ? w : 0.f;        // group-uniform predicate
            acc += w * u;
            dsum += w;
        }
    }
    float inv = (cnt > 0) ? 1.f / dsum : 0.f;
    acc *= inv;
    vf4 hd = h_dst4[(size_t)node * 16 + l16];
    ((vf4*)&ht[n][0])[l16] = hd;
    ((vf4*)&ht[n][64])[l16] = acc;
    __syncthreads();

    int o = t & 63;
    int g = t >> 6;                                // nodes g*4 .. g*4+3
    float bias = b[o];
    float a0 = bias, a1 = bias, a2 = bias, a3 = bias;
    const float* h0 = &ht[g * 4 + 0][0];
    const float* h1 = &ht[g * 4 + 1][0];
    const float* h2 = &ht[g * 4 + 2][0];
    const float* h3 = &ht[g * 4 + 3][0];
    #pragma unroll
    for (int k = 0; k < 128; k += 4) {
        float w0 = Wl[(k + 0) * 64 + o];
        float w1 = Wl[(k + 1) * 64 + o];
        float w2 = Wl[(k + 2) * 64 + o];
        float w3 = Wl[(k + 3) * 64 + o];
        vf4 p0 = *(const vf4*)&h0[k];
        vf4 p1 = *(const vf4*)&h1[k];
        vf4 p2 = *(const vf4*)&h2[k];
        vf4 p3 = *(const vf4*)&h3[k];
        a0 += p0[0]*w0 + p0[1]*w1 + p0[2]*w2 + p0[3]*w3;
        a1 += p1[0]*w0 + p1[1]*w1 + p1[2]*w2 + p1[3]*w3;
        a2 += p2[0]*w0 + p2[1]*w1 + p2[2]*w2 + p2[3]*w3;
        a3 += p3[0]*w0 + p3[1]*w1 + p3[2]*w2 + p3[3]*w3;
    }
    out[(size_t)(node0 + g * 4 + 0) * 64 + o] = a0;
    out[(size_t)(node0 + g * 4 + 1) * 64 + o] = a1;
    out[(size_t)(node0 + g * 4 + 2) * 64 + o] = a2;
    out[(size_t)(node0 + g * 4 + 3) * 64 + o] = a3;
}

extern "C" void kernel_launch(void* const* d_in, const int* in_sizes, int n_in,
                              void* d_out, int out_size, void* d_ws, size_t ws_size,
                              hipStream_t stream) {
    const float* h_src = (const float*)d_in[0];
    const float* h_dst = (const float*)d_in[1];
    const float* e     = (const float*)d_in[2];
    const int*   src   = (const int*)d_in[3];
    const int*   dst   = (const int*)d_in[4];
    const float* W     = (const float*)d_in[5];
    const float* b     = (const float*)d_in[6];
    float* out = (float*)d_out;

    // workspace: count[N] | slots[N*CAP int2]
    auto align256 = [](size_t x) { return (x + 255) & ~(size_t)255; };
    char* ws = (char*)d_ws;
    int*  count = (int*)ws;
    int2* slots = (int2*)(ws + align256((size_t)N_NODES * 4));

    hipMemsetAsync(count, 0, (size_t)N_NODES * 4, stream);

    k1_bucket<<<N_EDGES / 256, 256, 0, stream>>>(src, dst, count, slots);
    k2k3<<<N_NODES / 16, 256, 0, stream>>>(
        (const vf4*)h_src, (const vf4*)h_dst, (const vf4*)e,
        count, slots, W, b, out);
}